// Round 11
// baseline (195.215 us; speedup 1.0000x reference)
//
#include <hip/hip_runtime.h>
#include <math.h>

// ExplaiNN fused forward: B=128, N=300, L=600, K=19, C1=100, PS=7
// LC=582, LP=83, NC=2
#define EPS_ 1e-5f

// ---------------------------------------------------------------------------
// kP: pack conv weights cw4[c][kq][n][0..3] = conv_w[n][c*19+4kq+i] (i<19
// else 0): float4-per-lane so kA fetches 4 k's in one coalesced 16B load.
// ---------------------------------------------------------------------------
__global__ __launch_bounds__(256) void kP(const float* __restrict__ conv_w,
                                          float* __restrict__ cw4) {
    const int cq = blockIdx.x;              // 0..19
    const int c  = cq / 5;
    const int kq = cq - c * 5;
    for (int n = threadIdx.x; n < 300; n += 256) {
        float4 v;
        const int k0 = 4 * kq;
        v.x = (k0 + 0 < 19) ? conv_w[n * 76 + c * 19 + k0 + 0] : 0.f;
        v.y = (k0 + 1 < 19) ? conv_w[n * 76 + c * 19 + k0 + 1] : 0.f;
        v.z = (k0 + 2 < 19) ? conv_w[n * 76 + c * 19 + k0 + 2] : 0.f;
        v.w = (k0 + 3 < 19) ? conv_w[n * 76 + c * 19 + k0 + 3] : 0.f;
        reinterpret_cast<float4*>(cw4)[(c * 5 + kq) * 300 + n] = v;
    }
}

// ---------------------------------------------------------------------------
// kA: conv1d(4ch,K=19) + bias + bn1 + exp + maxpool(7,7).  UNCHANGED from R9
// (passed, 45us, VALUBusy 62%, issue floor ~28us): loop-interchanged
// persistent acc[4p x 7q]; cw4 float4 weight loads (20/task); x window
// uniform s_loads. grid 128*112 x 64: id = b*112+sub (112%8==0 ->
// same-XCD pooled lines).
// ---------------------------------------------------------------------------
__global__ __launch_bounds__(64) void kA(
        const float* __restrict__ x,        // [128][4][600]
        const float* __restrict__ cw4,      // [4][5][300][4]
        const float* __restrict__ conv_b,
        const float* __restrict__ g1, const float* __restrict__ b1,
        const float* __restrict__ m1, const float* __restrict__ v1,
        float* __restrict__ pooled)         // [300][83][128]
{
    const int id  = blockIdx.x;             // b*112 + sub
    const int b   = id / 112;
    const int sub = id - b * 112;
    if (sub >= 105) return;
    const int ng  = sub / 21;
    const int pc  = sub - ng * 21;
    const int p0c = pc * 4;
    const int p0  = (p0c > 79) ? 79 : p0c;  // p=79 done twice, same value
    const int lane = threadIdx.x;
    const int n   = ng * 64 + lane;
    const int nc  = (n < 300) ? n : 299;

    const float4* w4 = reinterpret_cast<const float4*>(cw4);

    float acc[28];
    #pragma unroll
    for (int i = 0; i < 28; ++i) acc[i] = 0.f;

    #pragma unroll 1
    for (int c = 0; c < 4; ++c) {
        const float* xc = x + b * 2400 + c * 600 + 7 * p0;  // uniform -> s_load
        float xw[46];
        #pragma unroll
        for (int j = 0; j < 46; ++j) xw[j] = xc[j];
        #pragma unroll
        for (int kq = 0; kq < 5; ++kq) {
            const float4 wv = w4[(c * 5 + kq) * 300 + nc];  // 4 k's, coalesced
            const int ni = (kq == 4) ? 3 : 4;               // k<19
            #pragma unroll
            for (int i = 0; i < ni; ++i) {
                const int k = 4 * kq + i;
                const float wvv = (i == 0) ? wv.x : (i == 1) ? wv.y
                                : (i == 2) ? wv.z : wv.w;
                #pragma unroll
                for (int p = 0; p < 4; ++p)
                    #pragma unroll
                    for (int q = 0; q < 7; ++q)
                        acc[p * 7 + q] = fmaf(xw[7 * p + q + k], wvv,
                                              acc[p * 7 + q]);
            }
        }
    }

    const float A1 = g1[nc] * rsqrtf(v1[nc] + EPS_);
    const float B1 = fmaf(A1, conv_b[nc] - m1[nc], b1[nc]);
    if (n < 300) {
        float* op = pooled + ((size_t)n * 83 + p0) * 128 + b;
        #pragma unroll
        for (int p = 0; p < 4; ++p) {
            float mx = -INFINITY;           // exp monotone: max before exp
            #pragma unroll
            for (int q = 0; q < 7; ++q)
                mx = fmaxf(mx, fmaf(A1, acc[p * 7 + q], B1));
            op[p * 128] = __expf(mx);
        }
    }
}

// ---------------------------------------------------------------------------
// kB: fc1(K=83) + bn2 + relu + fc2 + bn3 + relu.
// grid 600 x 256 (EXACT, no padding blocks): n = id>>1, bh = id&1.
// 4 waves, each owns a uniform 25-h chunk (single code path). lane = b.
// Weights read directly from ORIGINAL fc1_w[n][h][p] via wave-uniform
// s_loads (rows contiguous in p -> s_load_dwordx8 merge; ~2KB/wave live
// set, k$-resident). Pooled loads batched 8 deep (pv[8] independent
// coalesced loads in flight -> exposed L2 latency /8). acc[25]+pv[8] ~45
// VGPR. fc2 partial in-thread -> 4x64 LDS combine -> bn3+relu.
// ---------------------------------------------------------------------------
__global__ __launch_bounds__(256) void kB(
        const float* __restrict__ pooled,   // [300][83][128]
        const float* __restrict__ fc1w,     // [300][100][83]
        const float* __restrict__ fc1b,     // [300][100]
        const float* __restrict__ g2, const float* __restrict__ b2,
        const float* __restrict__ m2, const float* __restrict__ v2,
        const float* __restrict__ fc2w,     // [300][100]
        const float* __restrict__ fc2b,     // [300]
        const float* __restrict__ g3, const float* __restrict__ b3,
        const float* __restrict__ m3, const float* __restrict__ v3,
        float* __restrict__ sout)           // [300][128]
{
    __shared__ float sRed[4][64];
    const int id = blockIdx.x;              // 0..599
    const int n  = id >> 1;
    const int bh = id & 1;
    const int tid  = threadIdx.x;
    const int lane = tid & 63;
    const int wv   = __builtin_amdgcn_readfirstlane(tid >> 6);  // 0..3 uniform
    const int h0   = wv * 25;               // 0,25,50,75
    const int bb   = bh * 64 + lane;

    const float* pp = pooled + (size_t)n * 83 * 128 + bb;   // per-lane
    const float* wb = fc1w + (size_t)n * 8300 + h0 * 83;    // wave-uniform

    float acc[25];
    #pragma unroll
    for (int j = 0; j < 25; ++j) acc[j] = 0.f;

    for (int pb = 0; pb < 10; ++pb) {               // batches of 8 p
        float pv[8];
        #pragma unroll
        for (int i = 0; i < 8; ++i) pv[i] = pp[(pb * 8 + i) * 128];
        #pragma unroll
        for (int j = 0; j < 25; ++j) {
            const float* wr = wb + j * 83 + pb * 8; // uniform, contiguous
            #pragma unroll
            for (int i = 0; i < 8; ++i)
                acc[j] = fmaf(pv[i], wr[i], acc[j]); // v,s,v
        }
    }
    {   // tail p = 80..82
        float pv[3];
        #pragma unroll
        for (int i = 0; i < 3; ++i) pv[i] = pp[(80 + i) * 128];
        #pragma unroll
        for (int j = 0; j < 25; ++j) {
            const float* wr = wb + j * 83 + 80;
            #pragma unroll
            for (int i = 0; i < 3; ++i)
                acc[j] = fmaf(pv[i], wr[i], acc[j]);
        }
    }

    // bn2 + relu + fc2 partial (params at uniform addresses -> s_load)
    const int base = n * 100 + h0;
    float part = 0.f;
    #pragma unroll
    for (int j = 0; j < 25; ++j) {
        const float A2 = g2[base + j] * rsqrtf(v2[base + j] + EPS_);
        const float C2 = fmaf(A2, fc1b[base + j] - m2[base + j], b2[base + j]);
        const float act = fmaxf(fmaf(A2, acc[j], C2), 0.f);
        part = fmaf(act, fc2w[base + j], part);
    }
    sRed[wv][lane] = part;
    __syncthreads();
    if (tid < 64) {
        float s = sRed[0][tid] + sRed[1][tid] + sRed[2][tid] + sRed[3][tid];
        s += fc2b[n];
        const float A3 = g3[n] * rsqrtf(v3[n] + EPS_);
        const float z = fmaf(A3, s - m3[n], b3[n]);
        sout[n * 128 + bh * 64 + tid] = fmaxf(z, 0.f);
    }
}

// ---------------------------------------------------------------------------
// kC: out[b,c] = sum_n sout[n][b] * fw[c][n] + fb[c].  grid 128 x 64.
// ---------------------------------------------------------------------------
__global__ __launch_bounds__(64) void kC(
        const float* __restrict__ sout,     // [300][128]
        const float* __restrict__ fw,       // [2][300]
        const float* __restrict__ fb,
        float* __restrict__ out)            // [128][2]
{
    const int b = blockIdx.x, t = threadIdx.x;
    float a0 = 0.f, a1 = 0.f;
    for (int nn = t; nn < 300; nn += 64) {
        const float v = sout[nn * 128 + b];
        a0 = fmaf(v, fw[nn], a0);
        a1 = fmaf(v, fw[300 + nn], a1);
    }
    #pragma unroll
    for (int off = 32; off > 0; off >>= 1) {
        a0 += __shfl_xor(a0, off, 64);
        a1 += __shfl_xor(a1, off, 64);
    }
    if (t == 0) {
        out[b * 2 + 0] = a0 + fb[0];
        out[b * 2 + 1] = a1 + fb[1];
    }
}

extern "C" void kernel_launch(void* const* d_in, const int* in_sizes, int n_in,
                              void* d_out, int out_size, void* d_ws, size_t ws_size,
                              hipStream_t stream) {
    const float* x      = (const float*)d_in[0];
    const float* conv_w = (const float*)d_in[1];
    const float* conv_b = (const float*)d_in[2];
    const float* g1 = (const float*)d_in[3];
    const float* b1 = (const float*)d_in[4];
    const float* m1 = (const float*)d_in[5];
    const float* v1 = (const float*)d_in[6];
    const float* fc1_w = (const float*)d_in[7];
    const float* fc1_b = (const float*)d_in[8];
    const float* g2 = (const float*)d_in[9];
    const float* b2 = (const float*)d_in[10];
    const float* m2 = (const float*)d_in[11];
    const float* v2 = (const float*)d_in[12];
    const float* fc2_w = (const float*)d_in[13];
    const float* fc2_b = (const float*)d_in[14];
    const float* g3 = (const float*)d_in[15];
    const float* b3 = (const float*)d_in[16];
    const float* m3 = (const float*)d_in[17];
    const float* v3 = (const float*)d_in[18];
    const float* fw = (const float*)d_in[19];
    const float* fb = (const float*)d_in[20];
    float* out = (float*)d_out;

    float* pooled = (float*)d_ws;                        // 300*83*128 = 3187200
    float* cw4    = pooled + (size_t)300 * 83 * 128;     // 4*5*300*4  = 24000
    float* sout   = cw4 + 24000;                         // 300*128    = 38400
    // total ws: ~13 MB

    kP<<<20, 256, 0, stream>>>(conv_w, cw4);
    kA<<<128 * 112, 64, 0, stream>>>(x, cw4, conv_b, g1, b1, m1, v1, pooled);
    kB<<<600, 256, 0, stream>>>(pooled, fc1_w, fc1_b, g2, b2, m2, v2,
                                fc2_w, fc2_b, g3, b3, m3, v3, sout);
    kC<<<128, 64, 0, stream>>>(sout, fw, fb, out);
}

// Round 12
// 186.677 us; speedup vs baseline: 1.0457x; 1.0457x over previous
//
#include <hip/hip_runtime.h>
#include <math.h>

// ExplaiNN fused forward: B=128, N=300, L=600, K=19, C1=100, PS=7
// LC=582, LP=83, NC=2
#define EPS_ 1e-5f

// ---------------------------------------------------------------------------
// kP: blocks 0..299: fc1_w[n][h][p] -> w1Tp[n][p][hp] with hp padded to 112
// (h>=100 zero) via per-n LDS transpose (pad 101 -> conflict-free).
// Blocks 300..319: cw4[c][kq][n][0..3] float4 conv-weight pack for kA.
// ---------------------------------------------------------------------------
__global__ __launch_bounds__(256) void kP(const float* __restrict__ fc1w,
                                          const float* __restrict__ conv_w,
                                          float* __restrict__ w1Tp,
                                          float* __restrict__ cw4) {
    const int blk = blockIdx.x, tid = threadIdx.x;
    if (blk < 300) {
        __shared__ float sm[83 * 101];
        for (int i = tid; i < 8300; i += 256) {
            const int h = i / 83, p = i - h * 83;
            sm[p * 101 + h] = fc1w[(size_t)blk * 8300 + i];
        }
        __syncthreads();
        for (int i = tid; i < 9296; i += 256) {       // 83*112
            const int p = i / 112, h = i - p * 112;
            w1Tp[(size_t)blk * 9296 + i] = (h < 100) ? sm[p * 101 + h] : 0.f;
        }
    } else {
        const int cq = blk - 300;           // 0..19
        const int c  = cq / 5;
        const int kq = cq - c * 5;
        for (int n = tid; n < 300; n += 256) {
            float4 v;
            const int k0 = 4 * kq;
            v.x = (k0 + 0 < 19) ? conv_w[n * 76 + c * 19 + k0 + 0] : 0.f;
            v.y = (k0 + 1 < 19) ? conv_w[n * 76 + c * 19 + k0 + 1] : 0.f;
            v.z = (k0 + 2 < 19) ? conv_w[n * 76 + c * 19 + k0 + 2] : 0.f;
            v.w = (k0 + 3 < 19) ? conv_w[n * 76 + c * 19 + k0 + 3] : 0.f;
            reinterpret_cast<float4*>(cw4)[(c * 5 + kq) * 300 + n] = v;
        }
    }
}

// ---------------------------------------------------------------------------
// kA: conv1d(4ch,K=19) + bias + bn1 + exp + maxpool(7,7).  UNCHANGED (R9/R11,
// passed, 45us): loop-interchanged persistent acc[4p x 7q]; cw4 float4
// weight loads; x window uniform s_loads. grid 128*112 x 64.
// ---------------------------------------------------------------------------
__global__ __launch_bounds__(64) void kA(
        const float* __restrict__ x,        // [128][4][600]
        const float* __restrict__ cw4,      // [4][5][300][4]
        const float* __restrict__ conv_b,
        const float* __restrict__ g1, const float* __restrict__ b1,
        const float* __restrict__ m1, const float* __restrict__ v1,
        float* __restrict__ pooled)         // [300][83][128]
{
    const int id  = blockIdx.x;             // b*112 + sub
    const int b   = id / 112;
    const int sub = id - b * 112;
    if (sub >= 105) return;
    const int ng  = sub / 21;
    const int pc  = sub - ng * 21;
    const int p0c = pc * 4;
    const int p0  = (p0c > 79) ? 79 : p0c;  // p=79 done twice, same value
    const int lane = threadIdx.x;
    const int n   = ng * 64 + lane;
    const int nc  = (n < 300) ? n : 299;

    const float4* w4 = reinterpret_cast<const float4*>(cw4);

    float acc[28];
    #pragma unroll
    for (int i = 0; i < 28; ++i) acc[i] = 0.f;

    #pragma unroll 1
    for (int c = 0; c < 4; ++c) {
        const float* xc = x + b * 2400 + c * 600 + 7 * p0;  // uniform -> s_load
        float xw[46];
        #pragma unroll
        for (int j = 0; j < 46; ++j) xw[j] = xc[j];
        #pragma unroll
        for (int kq = 0; kq < 5; ++kq) {
            const float4 wv = w4[(c * 5 + kq) * 300 + nc];  // 4 k's, coalesced
            const int ni = (kq == 4) ? 3 : 4;               // k<19
            #pragma unroll
            for (int i = 0; i < ni; ++i) {
                const int k = 4 * kq + i;
                const float wvv = (i == 0) ? wv.x : (i == 1) ? wv.y
                                : (i == 2) ? wv.z : wv.w;
                #pragma unroll
                for (int p = 0; p < 4; ++p)
                    #pragma unroll
                    for (int q = 0; q < 7; ++q)
                        acc[p * 7 + q] = fmaf(xw[7 * p + q + k], wvv,
                                              acc[p * 7 + q]);
            }
        }
    }

    const float A1 = g1[nc] * rsqrtf(v1[nc] + EPS_);
    const float B1 = fmaf(A1, conv_b[nc] - m1[nc], b1[nc]);
    if (n < 300) {
        float* op = pooled + ((size_t)n * 83 + p0) * 128 + b;
        #pragma unroll
        for (int p = 0; p < 4; ++p) {
            float mx = -INFINITY;           // exp monotone: max before exp
            #pragma unroll
            for (int q = 0; q < 7; ++q)
                mx = fmaxf(mx, fmaf(A1, acc[p * 7 + q], B1));
            op[p * 128] = __expf(mx);
        }
    }
}

// ---------------------------------------------------------------------------
// kB: fc1(K=83) + bn2 + relu + fc2 + bn3 + relu.
// grid 300 x 256 (block = n). Weights staged ONCE into LDS via coalesced
// float4 VECTOR loads (R11's per-wave scalar streaming thrashed the k$:
// FETCH 28MB, 57us). Compute: 4 waves own 28-h chunks (h padded to 112,
// pad weights = 0); lane covers 2 batches via float2 pooled loads
// (coalesced 512B/wave); weights via BROADCAST ds_read_b128 (same addr all
// lanes -> ~free), 7 per p feeding 56 FMAs. acc[28][2]. fc2 partial
// in-thread -> 4x64x2 LDS combine -> bn3+relu. __launch_bounds__(256,2)
// caps VGPR at 256 so 2 blocks/CU stay co-resident.
// ---------------------------------------------------------------------------
__global__ __launch_bounds__(256, 2) void kB(
        const float* __restrict__ pooled,   // [300][83][128]
        const float* __restrict__ w1Tp,     // [300][83][112]
        const float* __restrict__ fc1b,     // [300][100]
        const float* __restrict__ g2, const float* __restrict__ b2,
        const float* __restrict__ m2, const float* __restrict__ v2,
        const float* __restrict__ fc2w,     // [300][100]
        const float* __restrict__ fc2b,     // [300]
        const float* __restrict__ g3, const float* __restrict__ b3,
        const float* __restrict__ m3, const float* __restrict__ v3,
        float* __restrict__ sout)           // [300][128]
{
    __shared__ __align__(16) float sW[83 * 112];    // 37.2 KB
    __shared__ float2 sRed[4][64];
    const int n   = blockIdx.x;
    const int tid = threadIdx.x;

    {   // stage weights: 2324 float4, coalesced vector loads
        const float4* src = reinterpret_cast<const float4*>(w1Tp + (size_t)n * 9296);
        float4* dst = reinterpret_cast<float4*>(sW);
        for (int i = tid; i < 2324; i += 256) dst[i] = src[i];
    }
    __syncthreads();

    const int lane = tid & 63;
    const int wv   = __builtin_amdgcn_readfirstlane(tid >> 6);  // 0..3
    const int h0   = wv * 28;               // 0,28,56,84 (pad h>=100 -> w=0)
    const int b0   = lane * 2;

    const float* pp = pooled + (size_t)n * 83 * 128 + b0;

    float acc[28][2];
    #pragma unroll
    for (int j = 0; j < 28; ++j) { acc[j][0] = 0.f; acc[j][1] = 0.f; }

    #pragma unroll 4
    for (int p = 0; p < 83; ++p) {
        const float2 pv = *reinterpret_cast<const float2*>(pp + p * 128);
        const float* wrow = sW + p * 112 + h0;
        #pragma unroll
        for (int jq = 0; jq < 7; ++jq) {
            const float4 w = *reinterpret_cast<const float4*>(wrow + 4 * jq);
            acc[jq * 4 + 0][0] = fmaf(w.x, pv.x, acc[jq * 4 + 0][0]);
            acc[jq * 4 + 0][1] = fmaf(w.x, pv.y, acc[jq * 4 + 0][1]);
            acc[jq * 4 + 1][0] = fmaf(w.y, pv.x, acc[jq * 4 + 1][0]);
            acc[jq * 4 + 1][1] = fmaf(w.y, pv.y, acc[jq * 4 + 1][1]);
            acc[jq * 4 + 2][0] = fmaf(w.z, pv.x, acc[jq * 4 + 2][0]);
            acc[jq * 4 + 2][1] = fmaf(w.z, pv.y, acc[jq * 4 + 2][1]);
            acc[jq * 4 + 3][0] = fmaf(w.w, pv.x, acc[jq * 4 + 3][0]);
            acc[jq * 4 + 3][1] = fmaf(w.w, pv.y, acc[jq * 4 + 3][1]);
        }
    }

    // bn2 + relu + fc2 partial over this wave's real h's (params uniform)
    const int nh = (wv < 3) ? 28 : 16;
    float p0s = 0.f, p1s = 0.f;
    for (int j = 0; j < nh; ++j) {
        const int hi = n * 100 + h0 + j;
        const float A2 = g2[hi] * rsqrtf(v2[hi] + EPS_);
        const float C2 = fmaf(A2, fc1b[hi] - m2[hi], b2[hi]);
        const float w2 = fc2w[hi];
        p0s = fmaf(fmaxf(fmaf(A2, acc[j][0], C2), 0.f), w2, p0s);
        p1s = fmaf(fmaxf(fmaf(A2, acc[j][1], C2), 0.f), w2, p1s);
    }
    sRed[wv][lane] = make_float2(p0s, p1s);
    __syncthreads();

    if (tid < 128) {                        // b == tid (b = 2*(tid>>1)+(tid&1))
        const int l = tid >> 1, r = tid & 1;
        float s = (r == 0)
            ? (sRed[0][l].x + sRed[1][l].x + sRed[2][l].x + sRed[3][l].x)
            : (sRed[0][l].y + sRed[1][l].y + sRed[2][l].y + sRed[3][l].y);
        s += fc2b[n];
        const float A3 = g3[n] * rsqrtf(v3[n] + EPS_);
        const float z = fmaf(A3, s - m3[n], b3[n]);
        sout[n * 128 + tid] = fmaxf(z, 0.f);
    }
}

// ---------------------------------------------------------------------------
// kC: out[b,c] = sum_n sout[n][b] * fw[c][n] + fb[c].  grid 128 x 64.
// ---------------------------------------------------------------------------
__global__ __launch_bounds__(64) void kC(
        const float* __restrict__ sout,     // [300][128]
        const float* __restrict__ fw,       // [2][300]
        const float* __restrict__ fb,
        float* __restrict__ out)            // [128][2]
{
    const int b = blockIdx.x, t = threadIdx.x;
    float a0 = 0.f, a1 = 0.f;
    for (int nn = t; nn < 300; nn += 64) {
        const float v = sout[nn * 128 + b];
        a0 = fmaf(v, fw[nn], a0);
        a1 = fmaf(v, fw[300 + nn], a1);
    }
    #pragma unroll
    for (int off = 32; off > 0; off >>= 1) {
        a0 += __shfl_xor(a0, off, 64);
        a1 += __shfl_xor(a1, off, 64);
    }
    if (t == 0) {
        out[b * 2 + 0] = a0 + fb[0];
        out[b * 2 + 1] = a1 + fb[1];
    }
}

extern "C" void kernel_launch(void* const* d_in, const int* in_sizes, int n_in,
                              void* d_out, int out_size, void* d_ws, size_t ws_size,
                              hipStream_t stream) {
    const float* x      = (const float*)d_in[0];
    const float* conv_w = (const float*)d_in[1];
    const float* conv_b = (const float*)d_in[2];
    const float* g1 = (const float*)d_in[3];
    const float* b1 = (const float*)d_in[4];
    const float* m1 = (const float*)d_in[5];
    const float* v1 = (const float*)d_in[6];
    const float* fc1_w = (const float*)d_in[7];
    const float* fc1_b = (const float*)d_in[8];
    const float* g2 = (const float*)d_in[9];
    const float* b2 = (const float*)d_in[10];
    const float* m2 = (const float*)d_in[11];
    const float* v2 = (const float*)d_in[12];
    const float* fc2_w = (const float*)d_in[13];
    const float* fc2_b = (const float*)d_in[14];
    const float* g3 = (const float*)d_in[15];
    const float* b3 = (const float*)d_in[16];
    const float* m3 = (const float*)d_in[17];
    const float* v3 = (const float*)d_in[18];
    const float* fw = (const float*)d_in[19];
    const float* fb = (const float*)d_in[20];
    float* out = (float*)d_out;

    float* pooled = (float*)d_ws;                        // 300*83*128 = 3187200
    float* w1Tp   = pooled + (size_t)300 * 83 * 128;     // 300*9296   = 2788800
    float* cw4    = w1Tp + (size_t)300 * 9296;           // 4*5*300*4  = 24000
    float* sout   = cw4 + 24000;                         // 300*128    = 38400
    // total ws: ~24.2 MB

    kP<<<320, 256, 0, stream>>>(fc1_w, conv_w, w1Tp, cw4);
    kA<<<128 * 112, 64, 0, stream>>>(x, cw4, conv_b, g1, b1, m1, v1, pooled);
    kB<<<300, 256, 0, stream>>>(pooled, w1Tp, fc1_b, g2, b2, m2, v2,
                                fc2_w, fc2_b, g3, b3, m3, v3, sout);
    kC<<<128, 64, 0, stream>>>(sout, fw, fb, out);
}

// Round 13
// 183.878 us; speedup vs baseline: 1.0617x; 1.0152x over previous
//
#include <hip/hip_runtime.h>
#include <math.h>

// ExplaiNN fused forward: B=128, N=300, L=600, K=19, C1=100, PS=7
// LC=582, LP=83, NC=2
#define EPS_ 1e-5f

// ---------------------------------------------------------------------------
// kP: cw4[c][kq][n][0..3] float4 conv-weight pack for kA (20 blocks, ~2us).
// (R12's 300-block fc1_w transpose is gone: kB transposes in its own LDS
// staging pass -> saves ~8us kernel time + 22 MB of HBM round-trip.)
// ---------------------------------------------------------------------------
__global__ __launch_bounds__(256) void kP(const float* __restrict__ conv_w,
                                          float* __restrict__ cw4) {
    const int cq = blockIdx.x;              // 0..19
    const int c  = cq / 5;
    const int kq = cq - c * 5;
    for (int n = threadIdx.x; n < 300; n += 256) {
        float4 v;
        const int k0 = 4 * kq;
        v.x = (k0 + 0 < 19) ? conv_w[n * 76 + c * 19 + k0 + 0] : 0.f;
        v.y = (k0 + 1 < 19) ? conv_w[n * 76 + c * 19 + k0 + 1] : 0.f;
        v.z = (k0 + 2 < 19) ? conv_w[n * 76 + c * 19 + k0 + 2] : 0.f;
        v.w = (k0 + 3 < 19) ? conv_w[n * 76 + c * 19 + k0 + 3] : 0.f;
        reinterpret_cast<float4*>(cw4)[(c * 5 + kq) * 300 + n] = v;
    }
}

// ---------------------------------------------------------------------------
// kA: conv1d(4ch,K=19) + bias + bn1 + exp + maxpool(7,7).
// R9 structure, p-tile widened 4 -> 6: per task 3192 FMAs vs 240 uniform
// x s_loads (ratio 13.3 vs R9's 2.9) and 168 FMAs per weight float4 --
// the 17us of R9/R12 stall was load-amortization, not occupancy (VALUBusy
// 61% at 3 waves/SIMD for 4 rounds). acc[42] persistent (un-remat-able),
// xw[60] wave-uniform -> SGPRs (R9-proven: VGPR=32 with xw[46]).
// grid 128*72 x 64: id = b*72+sub, sub = ng*14+pc < 70 (72%8==0 -> all b of
// one (ng,pc) on the same XCD; WRITE_SIZE ~12.6MB ideal since R5).
// p0 clamped to 77: p=77..82 overlap-computed by pc=12/13, same values.
// ---------------------------------------------------------------------------
__global__ __launch_bounds__(64) void kA(
        const float* __restrict__ x,        // [128][4][600]
        const float* __restrict__ cw4,      // [4][5][300][4]
        const float* __restrict__ conv_b,
        const float* __restrict__ g1, const float* __restrict__ b1,
        const float* __restrict__ m1, const float* __restrict__ v1,
        float* __restrict__ pooled)         // [300][83][128]
{
    const int id  = blockIdx.x;             // b*72 + sub
    const int b   = id / 72;
    const int sub = id - b * 72;
    if (sub >= 70) return;
    const int ng  = sub / 14;               // 0..4
    const int pc  = sub - ng * 14;          // 0..13
    const int p0c = pc * 6;
    const int p0  = (p0c > 77) ? 77 : p0c;
    const int lane = threadIdx.x;
    const int n   = ng * 64 + lane;
    const int nc  = (n < 300) ? n : 299;

    const float4* w4 = reinterpret_cast<const float4*>(cw4);

    float acc[42];
    #pragma unroll
    for (int i = 0; i < 42; ++i) acc[i] = 0.f;

    #pragma unroll 1
    for (int c = 0; c < 4; ++c) {
        const float* xc = x + b * 2400 + c * 600 + 7 * p0;  // uniform -> s_load
        float xw[60];                       // max idx 7*77+59=598 < 600
        #pragma unroll
        for (int j = 0; j < 60; ++j) xw[j] = xc[j];
        #pragma unroll
        for (int kq = 0; kq < 5; ++kq) {
            const float4 wv = w4[(c * 5 + kq) * 300 + nc];  // 4 k's, coalesced
            const int ni = (kq == 4) ? 3 : 4;               // k<19
            #pragma unroll
            for (int i = 0; i < ni; ++i) {
                const int k = 4 * kq + i;
                const float wvv = (i == 0) ? wv.x : (i == 1) ? wv.y
                                : (i == 2) ? wv.z : wv.w;
                #pragma unroll
                for (int p = 0; p < 6; ++p)
                    #pragma unroll
                    for (int q = 0; q < 7; ++q)
                        acc[p * 7 + q] = fmaf(xw[7 * p + q + k], wvv,
                                              acc[p * 7 + q]);
            }
        }
    }

    const float A1 = g1[nc] * rsqrtf(v1[nc] + EPS_);
    const float B1 = fmaf(A1, conv_b[nc] - m1[nc], b1[nc]);
    if (n < 300) {
        float* op = pooled + ((size_t)n * 83 + p0) * 128 + b;
        #pragma unroll
        for (int p = 0; p < 6; ++p) {
            float mx = -INFINITY;           // exp monotone: max before exp
            #pragma unroll
            for (int q = 0; q < 7; ++q)
                mx = fmaxf(mx, fmaf(A1, acc[p * 7 + q], B1));
            op[p * 128] = __expf(mx);
        }
    }
}

// ---------------------------------------------------------------------------
// kB: fc1(K=83) + bn2 + relu + fc2 + bn3 + relu.  (R12 structure, passed;
// staging now reads ORIGINAL fc1_w coalesced and transposes into LDS:
// scatter stride 112 -> bank stride 16 -> 2-way conflict = free [m136].)
// grid 300 x 256 (block = n). 4 waves own 28-h chunks (h padded to 112,
// pad weights 0); lane covers 2 batches via float2 pooled loads; weights
// via broadcast ds_read_b128. acc[28][2]; fc2 partial in-thread ->
// 4x64x2 LDS combine -> bn3+relu.
// ---------------------------------------------------------------------------
__global__ __launch_bounds__(256, 2) void kB(
        const float* __restrict__ pooled,   // [300][83][128]
        const float* __restrict__ fc1w,     // [300][100][83]
        const float* __restrict__ fc1b,     // [300][100]
        const float* __restrict__ g2, const float* __restrict__ b2,
        const float* __restrict__ m2, const float* __restrict__ v2,
        const float* __restrict__ fc2w,     // [300][100]
        const float* __restrict__ fc2b,     // [300]
        const float* __restrict__ g3, const float* __restrict__ b3,
        const float* __restrict__ m3, const float* __restrict__ v3,
        float* __restrict__ sout)           // [300][128]
{
    __shared__ __align__(16) float sW[83 * 112];    // 37.2 KB
    __shared__ float2 sRed[4][64];
    const int n   = blockIdx.x;
    const int tid = threadIdx.x;

    {   // stage + transpose: coalesced global reads, LDS scatter (2-way, free)
        const float* src = fc1w + (size_t)n * 8300;
        for (int i = tid; i < 8300; i += 256) {
            const int h = i / 83, p = i - h * 83;
            sW[p * 112 + h] = src[i];
        }
        for (int i = tid; i < 996; i += 256) {      // zero pad h=100..111
            const int p = i / 12, h = 100 + (i - p * 12);
            sW[p * 112 + h] = 0.f;
        }
    }
    __syncthreads();

    const int lane = tid & 63;
    const int wv   = __builtin_amdgcn_readfirstlane(tid >> 6);  // 0..3
    const int h0   = wv * 28;               // 0,28,56,84 (pad h>=100 -> w=0)
    const int b0   = lane * 2;

    const float* pp = pooled + (size_t)n * 83 * 128 + b0;

    float acc[28][2];
    #pragma unroll
    for (int j = 0; j < 28; ++j) { acc[j][0] = 0.f; acc[j][1] = 0.f; }

    #pragma unroll 4
    for (int p = 0; p < 83; ++p) {
        const float2 pv = *reinterpret_cast<const float2*>(pp + p * 128);
        const float* wrow = sW + p * 112 + h0;
        #pragma unroll
        for (int jq = 0; jq < 7; ++jq) {
            const float4 w = *reinterpret_cast<const float4*>(wrow + 4 * jq);
            acc[jq * 4 + 0][0] = fmaf(w.x, pv.x, acc[jq * 4 + 0][0]);
            acc[jq * 4 + 0][1] = fmaf(w.x, pv.y, acc[jq * 4 + 0][1]);
            acc[jq * 4 + 1][0] = fmaf(w.y, pv.x, acc[jq * 4 + 1][0]);
            acc[jq * 4 + 1][1] = fmaf(w.y, pv.y, acc[jq * 4 + 1][1]);
            acc[jq * 4 + 2][0] = fmaf(w.z, pv.x, acc[jq * 4 + 2][0]);
            acc[jq * 4 + 2][1] = fmaf(w.z, pv.y, acc[jq * 4 + 2][1]);
            acc[jq * 4 + 3][0] = fmaf(w.w, pv.x, acc[jq * 4 + 3][0]);
            acc[jq * 4 + 3][1] = fmaf(w.w, pv.y, acc[jq * 4 + 3][1]);
        }
    }

    // bn2 + relu + fc2 partial over this wave's real h's (params uniform)
    const int nh = (wv < 3) ? 28 : 16;
    float p0s = 0.f, p1s = 0.f;
    for (int j = 0; j < nh; ++j) {
        const int hi = n * 100 + h0 + j;
        const float A2 = g2[hi] * rsqrtf(v2[hi] + EPS_);
        const float C2 = fmaf(A2, fc1b[hi] - m2[hi], b2[hi]);
        const float w2 = fc2w[hi];
        p0s = fmaf(fmaxf(fmaf(A2, acc[j][0], C2), 0.f), w2, p0s);
        p1s = fmaf(fmaxf(fmaf(A2, acc[j][1], C2), 0.f), w2, p1s);
    }
    sRed[wv][lane] = make_float2(p0s, p1s);
    __syncthreads();

    if (tid < 128) {                        // b == tid
        const int l = tid >> 1, r = tid & 1;
        float s = (r == 0)
            ? (sRed[0][l].x + sRed[1][l].x + sRed[2][l].x + sRed[3][l].x)
            : (sRed[0][l].y + sRed[1][l].y + sRed[2][l].y + sRed[3][l].y);
        s += fc2b[n];
        const float A3 = g3[n] * rsqrtf(v3[n] + EPS_);
        const float z = fmaf(A3, s - m3[n], b3[n]);
        sout[n * 128 + tid] = fmaxf(z, 0.f);
    }
}

// ---------------------------------------------------------------------------
// kC: out[b,c] = sum_n sout[n][b] * fw[c][n] + fb[c].  grid 128 x 64.
// ---------------------------------------------------------------------------
__global__ __launch_bounds__(64) void kC(
        const float* __restrict__ sout,     // [300][128]
        const float* __restrict__ fw,       // [2][300]
        const float* __restrict__ fb,
        float* __restrict__ out)            // [128][2]
{
    const int b = blockIdx.x, t = threadIdx.x;
    float a0 = 0.f, a1 = 0.f;
    for (int nn = t; nn < 300; nn += 64) {
        const float v = sout[nn * 128 + b];
        a0 = fmaf(v, fw[nn], a0);
        a1 = fmaf(v, fw[300 + nn], a1);
    }
    #pragma unroll
    for (int off = 32; off > 0; off >>= 1) {
        a0 += __shfl_xor(a0, off, 64);
        a1 += __shfl_xor(a1, off, 64);
    }
    if (t == 0) {
        out[b * 2 + 0] = a0 + fb[0];
        out[b * 2 + 1] = a1 + fb[1];
    }
}

extern "C" void kernel_launch(void* const* d_in, const int* in_sizes, int n_in,
                              void* d_out, int out_size, void* d_ws, size_t ws_size,
                              hipStream_t stream) {
    const float* x      = (const float*)d_in[0];
    const float* conv_w = (const float*)d_in[1];
    const float* conv_b = (const float*)d_in[2];
    const float* g1 = (const float*)d_in[3];
    const float* b1 = (const float*)d_in[4];
    const float* m1 = (const float*)d_in[5];
    const float* v1 = (const float*)d_in[6];
    const float* fc1_w = (const float*)d_in[7];
    const float* fc1_b = (const float*)d_in[8];
    const float* g2 = (const float*)d_in[9];
    const float* b2 = (const float*)d_in[10];
    const float* m2 = (const float*)d_in[11];
    const float* v2 = (const float*)d_in[12];
    const float* fc2_w = (const float*)d_in[13];
    const float* fc2_b = (const float*)d_in[14];
    const float* g3 = (const float*)d_in[15];
    const float* b3 = (const float*)d_in[16];
    const float* m3 = (const float*)d_in[17];
    const float* v3 = (const float*)d_in[18];
    const float* fw = (const float*)d_in[19];
    const float* fb = (const float*)d_in[20];
    float* out = (float*)d_out;

    float* pooled = (float*)d_ws;                        // 300*83*128 = 3187200
    float* cw4    = pooled + (size_t)300 * 83 * 128;     // 4*5*300*4  = 24000
    float* sout   = cw4 + 24000;                         // 300*128    = 38400
    // total ws: ~13 MB

    kP<<<20, 256, 0, stream>>>(conv_w, cw4);
    kA<<<128 * 72, 64, 0, stream>>>(x, cw4, conv_b, g1, b1, m1, v1, pooled);
    kB<<<300, 256, 0, stream>>>(pooled, fc1_w, fc1_b, g2, b2, m2, v2,
                                fc2_w, fc2_b, g3, b3, m3, v3, sout);
    kC<<<128, 64, 0, stream>>>(sout, fw, fb, out);
}

// Round 14
// 174.262 us; speedup vs baseline: 1.1202x; 1.0552x over previous
//
#include <hip/hip_runtime.h>
#include <math.h>

// ExplaiNN fused forward: B=128, N=300, L=600, K=19, C1=100, PS=7
// LC=582, LP=83, NC=2
#define EPS_ 1e-5f

// ---------------------------------------------------------------------------
// kP: cw4[c][kq][n][0..3] float4 conv-weight pack for kA (20 blocks, ~2us).
// ---------------------------------------------------------------------------
__global__ __launch_bounds__(256) void kP(const float* __restrict__ conv_w,
                                          float* __restrict__ cw4) {
    const int cq = blockIdx.x;              // 0..19
    const int c  = cq / 5;
    const int kq = cq - c * 5;
    for (int n = threadIdx.x; n < 300; n += 256) {
        float4 v;
        const int k0 = 4 * kq;
        v.x = (k0 + 0 < 19) ? conv_w[n * 76 + c * 19 + k0 + 0] : 0.f;
        v.y = (k0 + 1 < 19) ? conv_w[n * 76 + c * 19 + k0 + 1] : 0.f;
        v.z = (k0 + 2 < 19) ? conv_w[n * 76 + c * 19 + k0 + 2] : 0.f;
        v.w = (k0 + 3 < 19) ? conv_w[n * 76 + c * 19 + k0 + 3] : 0.f;
        reinterpret_cast<float4*>(cw4)[(c * 5 + kq) * 300 + n] = v;
    }
}

// ---------------------------------------------------------------------------
// kA: conv1d(4ch,K=19) + bias + bn1 + exp + maxpool(7,7).  R9-EXACT (best
// measured: 44.9-45.5us, VGPR=32, VALUBusy ~61%). Loop-interchanged
// persistent acc[4p x 7q]; cw4 float4 weight loads (20/task, each feeding
// 112 FMAs); x window wave-uniform -> s_loads. grid 128*112 x 64:
// id = b*112+sub (112%8==0 -> same-XCD pooled lines). R13's 6-wide tile
// (acc[42]) overflowed the allocator (VGPR=40 < 42) and regressed.
// ---------------------------------------------------------------------------
__global__ __launch_bounds__(64) void kA(
        const float* __restrict__ x,        // [128][4][600]
        const float* __restrict__ cw4,      // [4][5][300][4]
        const float* __restrict__ conv_b,
        const float* __restrict__ g1, const float* __restrict__ b1,
        const float* __restrict__ m1, const float* __restrict__ v1,
        float* __restrict__ pooled)         // [300][83][128]
{
    const int id  = blockIdx.x;             // b*112 + sub
    const int b   = id / 112;
    const int sub = id - b * 112;
    if (sub >= 105) return;
    const int ng  = sub / 21;
    const int pc  = sub - ng * 21;
    const int p0c = pc * 4;
    const int p0  = (p0c > 79) ? 79 : p0c;  // p=79 done twice, same value
    const int lane = threadIdx.x;
    const int n   = ng * 64 + lane;
    const int nc  = (n < 300) ? n : 299;

    const float4* w4 = reinterpret_cast<const float4*>(cw4);

    float acc[28];
    #pragma unroll
    for (int i = 0; i < 28; ++i) acc[i] = 0.f;

    #pragma unroll 1
    for (int c = 0; c < 4; ++c) {
        const float* xc = x + b * 2400 + c * 600 + 7 * p0;  // uniform -> s_load
        float xw[46];
        #pragma unroll
        for (int j = 0; j < 46; ++j) xw[j] = xc[j];
        #pragma unroll
        for (int kq = 0; kq < 5; ++kq) {
            const float4 wv = w4[(c * 5 + kq) * 300 + nc];  // 4 k's, coalesced
            const int ni = (kq == 4) ? 3 : 4;               // k<19
            #pragma unroll
            for (int i = 0; i < ni; ++i) {
                const int k = 4 * kq + i;
                const float wvv = (i == 0) ? wv.x : (i == 1) ? wv.y
                                : (i == 2) ? wv.z : wv.w;
                #pragma unroll
                for (int p = 0; p < 4; ++p)
                    #pragma unroll
                    for (int q = 0; q < 7; ++q)
                        acc[p * 7 + q] = fmaf(xw[7 * p + q + k], wvv,
                                              acc[p * 7 + q]);
            }
        }
    }

    const float A1 = g1[nc] * rsqrtf(v1[nc] + EPS_);
    const float B1 = fmaf(A1, conv_b[nc] - m1[nc], b1[nc]);
    if (n < 300) {
        float* op = pooled + ((size_t)n * 83 + p0) * 128 + b;
        #pragma unroll
        for (int p = 0; p < 4; ++p) {
            float mx = -INFINITY;           // exp monotone: max before exp
            #pragma unroll
            for (int q = 0; q < 7; ++q)
                mx = fmaxf(mx, fmaf(A1, acc[p * 7 + q], B1));
            op[p * 128] = __expf(mx);
        }
    }
}

// ---------------------------------------------------------------------------
// kB: fc1(K=83) + bn2 + relu + fc2 + bn3 + relu.
// R13 post-mortem: 300 blocks = 1.17 blocks/CU = ~1 wave/SIMD -> 90% stall
// (VALUBusy 13.7%, Occ 8.7%); staging stride 112 hit 2-8 banks (1.06M
// conflict cycles). Fix: grid 600 x 256 (block = (n, b-half) -> 2.3
// blocks/CU, 9+ waves/CU) and LDS row stride 116 (116%32=20, gcd 4 ->
// 8-way on the ~33 staging writes/thread only ~ free [m136]; float4 reads
// stay 16B-aligned, broadcast reads conflict-free). lane = b: one coalesced
// float load per p (256B/wave); weights broadcast ds_read_b128. acc[28];
// fc2 partial in-thread -> 4x64 LDS combine -> bn3+relu.
// ---------------------------------------------------------------------------
__global__ __launch_bounds__(256, 2) void kB(
        const float* __restrict__ pooled,   // [300][83][128]
        const float* __restrict__ fc1w,     // [300][100][83]
        const float* __restrict__ fc1b,     // [300][100]
        const float* __restrict__ g2, const float* __restrict__ b2,
        const float* __restrict__ m2, const float* __restrict__ v2,
        const float* __restrict__ fc2w,     // [300][100]
        const float* __restrict__ fc2b,     // [300]
        const float* __restrict__ g3, const float* __restrict__ b3,
        const float* __restrict__ m3, const float* __restrict__ v3,
        float* __restrict__ sout)           // [300][128]
{
    __shared__ __align__(16) float sW[83 * 116];    // 38.5 KB
    __shared__ float sRed[4][64];
    const int id  = blockIdx.x;             // 0..599
    const int n   = id >> 1;
    const int bh  = id & 1;
    const int tid = threadIdx.x;

    {   // stage + transpose: coalesced global reads; 8-way write aliasing ~free
        const float* src = fc1w + (size_t)n * 8300;
        for (int i = tid; i < 8300; i += 256) {
            const int h = i / 83, p = i - h * 83;
            sW[p * 116 + h] = src[i];
        }
        for (int i = tid; i < 83 * 16; i += 256) {  // zero pad h=100..115
            const int p = i / 16, h = 100 + (i - p * 16);
            sW[p * 116 + h] = 0.f;
        }
    }
    __syncthreads();

    const int lane = tid & 63;
    const int wv   = __builtin_amdgcn_readfirstlane(tid >> 6);  // 0..3
    const int h0   = wv * 28;               // 0,28,56,84 (pad h>=100 -> w=0)
    const int bb   = bh * 64 + lane;

    const float* pp = pooled + (size_t)n * 83 * 128 + bb;

    float acc[28];
    #pragma unroll
    for (int j = 0; j < 28; ++j) acc[j] = 0.f;

    #pragma unroll 4
    for (int p = 0; p < 83; ++p) {
        const float pv = pp[p * 128];                       // coalesced 256B
        const float* wrow = sW + p * 116 + h0;
        #pragma unroll
        for (int jq = 0; jq < 7; ++jq) {
            const float4 w = *reinterpret_cast<const float4*>(wrow + 4 * jq);
            acc[jq * 4 + 0] = fmaf(w.x, pv, acc[jq * 4 + 0]);
            acc[jq * 4 + 1] = fmaf(w.y, pv, acc[jq * 4 + 1]);
            acc[jq * 4 + 2] = fmaf(w.z, pv, acc[jq * 4 + 2]);
            acc[jq * 4 + 3] = fmaf(w.w, pv, acc[jq * 4 + 3]);
        }
    }

    // bn2 + relu + fc2 partial over this wave's real h's (params uniform)
    const int nh = (wv < 3) ? 28 : 16;
    float part = 0.f;
    for (int j = 0; j < nh; ++j) {
        const int hi = n * 100 + h0 + j;
        const float A2 = g2[hi] * rsqrtf(v2[hi] + EPS_);
        const float C2 = fmaf(A2, fc1b[hi] - m2[hi], b2[hi]);
        part = fmaf(fmaxf(fmaf(A2, acc[j], C2), 0.f), fc2w[hi], part);
    }
    sRed[wv][lane] = part;
    __syncthreads();

    if (tid < 64) {
        float s = sRed[0][tid] + sRed[1][tid] + sRed[2][tid] + sRed[3][tid];
        s += fc2b[n];
        const float A3 = g3[n] * rsqrtf(v3[n] + EPS_);
        const float z = fmaf(A3, s - m3[n], b3[n]);
        sout[n * 128 + bh * 64 + tid] = fmaxf(z, 0.f);
    }
}

// ---------------------------------------------------------------------------
// kC: out[b,c] = sum_n sout[n][b] * fw[c][n] + fb[c].  grid 128 x 64.
// ---------------------------------------------------------------------------
__global__ __launch_bounds__(64) void kC(
        const float* __restrict__ sout,     // [300][128]
        const float* __restrict__ fw,       // [2][300]
        const float* __restrict__ fb,
        float* __restrict__ out)            // [128][2]
{
    const int b = blockIdx.x, t = threadIdx.x;
    float a0 = 0.f, a1 = 0.f;
    for (int nn = t; nn < 300; nn += 64) {
        const float v = sout[nn * 128 + b];
        a0 = fmaf(v, fw[nn], a0);
        a1 = fmaf(v, fw[300 + nn], a1);
    }
    #pragma unroll
    for (int off = 32; off > 0; off >>= 1) {
        a0 += __shfl_xor(a0, off, 64);
        a1 += __shfl_xor(a1, off, 64);
    }
    if (t == 0) {
        out[b * 2 + 0] = a0 + fb[0];
        out[b * 2 + 1] = a1 + fb[1];
    }
}

extern "C" void kernel_launch(void* const* d_in, const int* in_sizes, int n_in,
                              void* d_out, int out_size, void* d_ws, size_t ws_size,
                              hipStream_t stream) {
    const float* x      = (const float*)d_in[0];
    const float* conv_w = (const float*)d_in[1];
    const float* conv_b = (const float*)d_in[2];
    const float* g1 = (const float*)d_in[3];
    const float* b1 = (const float*)d_in[4];
    const float* m1 = (const float*)d_in[5];
    const float* v1 = (const float*)d_in[6];
    const float* fc1_w = (const float*)d_in[7];
    const float* fc1_b = (const float*)d_in[8];
    const float* g2 = (const float*)d_in[9];
    const float* b2 = (const float*)d_in[10];
    const float* m2 = (const float*)d_in[11];
    const float* v2 = (const float*)d_in[12];
    const float* fc2_w = (const float*)d_in[13];
    const float* fc2_b = (const float*)d_in[14];
    const float* g3 = (const float*)d_in[15];
    const float* b3 = (const float*)d_in[16];
    const float* m3 = (const float*)d_in[17];
    const float* v3 = (const float*)d_in[18];
    const float* fw = (const float*)d_in[19];
    const float* fb = (const float*)d_in[20];
    float* out = (float*)d_out;

    float* pooled = (float*)d_ws;                        // 300*83*128 = 3187200
    float* cw4    = pooled + (size_t)300 * 83 * 128;     // 4*5*300*4  = 24000
    float* sout   = cw4 + 24000;                         // 300*128    = 38400
    // total ws: ~13 MB

    kP<<<20, 256, 0, stream>>>(conv_w, cw4);
    kA<<<128 * 112, 64, 0, stream>>>(x, cw4, conv_b, g1, b1, m1, v1, pooled);
    kB<<<600, 256, 0, stream>>>(pooled, fc1_w, fc1_b, g2, b2, m2, v2,
                                fc2_w, fc2_b, g3, b3, m3, v3, sout);
    kC<<<128, 64, 0, stream>>>(sout, fw, fb, out);
}